// Round 5
// baseline (215.079 us; speedup 1.0000x reference)
//
#include <hip/hip_runtime.h>
#include <hip/hip_bf16.h>
#include <stdint.h>

typedef unsigned short ushort_t;
typedef __attribute__((ext_vector_type(8))) __bf16 bf16x8;
typedef __attribute__((ext_vector_type(4))) float f32x4;

typedef const __attribute__((address_space(1))) uint32_t* gptr_t;
typedef __attribute__((address_space(3))) uint32_t* lptr_t;

__device__ __forceinline__ ushort_t f2bf(float f) {
  union { float f; uint32_t u; } x; x.f = f;
  uint32_t u = x.u;
  uint32_t r = (u + 0x7fffu + ((u >> 16) & 1u)) >> 16;
  return (ushort_t)r;
}

__device__ __forceinline__ uint32_t cvt_pk_bf16(float lo, float hi) {
  uint32_t r;
  asm("v_cvt_pk_bf16_f32 %0, %1, %2" : "=v"(r) : "v"(lo), "v"(hi));
  return r;
}

__device__ __forceinline__ void gload_lds16(const void* g, void* l) {
  __builtin_amdgcn_global_load_lds((gptr_t)g, (lptr_t)l, 16, 0, 0);
}

__device__ __forceinline__ void lgkm0_fence() {
  asm volatile("s_waitcnt lgkmcnt(0)" ::: "memory");
  __builtin_amdgcn_sched_barrier(0);
}
__device__ __forceinline__ void waitvm4() { asm volatile("s_waitcnt vmcnt(4)" ::: "memory"); }
__device__ __forceinline__ void waitvm0() { asm volatile("s_waitcnt vmcnt(0)" ::: "memory"); }

// ---------------- cast x (fp32 -> bf16) ----------------
__global__ void cast_x(const float* __restrict__ in, ushort_t* __restrict__ out, int n) {
  const int idx = (blockIdx.x * 256 + threadIdx.x) * 4;
  if (idx < n) {
    const float4 v = *(const float4*)(in + idx);
    ushort4 o;
    o.x = f2bf(v.x); o.y = f2bf(v.y); o.z = f2bf(v.z); o.w = f2bf(v.w);
    *(ushort4*)(out + idx) = o;
  }
}

// ---------------- transpose + cast weights: in[K][N] fp32 -> out[N][K] bf16 ----------------
__global__ void transpose_cast(const float* __restrict__ in, ushort_t* __restrict__ out, int K, int N) {
  __shared__ ushort_t t[32][33];
  const int n0 = blockIdx.x * 32, k0 = blockIdx.y * 32;
  const int c = threadIdx.x & 31, r0 = threadIdx.x >> 5;
#pragma unroll
  for (int i = 0; i < 4; ++i) {
    const int r = r0 + i * 8;
    t[r][c] = f2bf(in[(size_t)(k0 + r) * N + n0 + c]);
  }
  __syncthreads();
#pragma unroll
  for (int i = 0; i < 4; ++i) {
    const int r = r0 + i * 8;
    out[(size_t)(n0 + r) * K + k0 + c] = t[c][r];
  }
}

// ================= 256x256 8-phase GEMM (T2+T3+T4+T5), QKV scatter epilogue =================
// A[M,K] * Bt[N,K]^T + bias -> Q,K -> [BH][S][D] (Q pre-scaled), V -> [BH][D][S].
// st_16x32 LDS swizzle: byte_off ^= ((byte_off>>9)&1)<<5, applied as pre-swizzled global
// source on stage (linear gload_lds dest) + swizzled ds_read. Counted vmcnt(4) at phases
// 4/8 only; raw s_barrier (no __syncthreads -> no vmcnt drain).

__device__ __forceinline__ void stage_half(const ushort_t* g, int ldk,
                                           ushort_t* lds, int tid) {
  const int r0 = tid >> 3;                       // 0..63
  const int ch = tid & 7;                        // 16B chunk in 128B row
  const int chs = ch ^ (((tid >> 5) & 1) << 1);  // pre-swizzle source chunk by row bit2
#pragma unroll
  for (int j = 0; j < 2; ++j) {
    const int row = j * 64 + r0;
    gload_lds16(g + (size_t)row * ldk + chs * 8, lds + row * 64 + ch * 8);
  }
}

__device__ __forceinline__ bf16x8 read_frag(const ushort_t* tile, int row, int kf, int lhi) {
  const int bc = (kf * 64 + lhi * 16) ^ (((row >> 2) & 1) << 5);
  return *(const bf16x8*)((const char*)(tile + row * 64) + bc);
}

__device__ __forceinline__ void lda4(bf16x8 (&a)[4][2], const ushort_t* At,
                                     int mlo, int wm, int l16, int lhi) {
#pragma unroll
  for (int mi = 0; mi < 4; ++mi)
#pragma unroll
    for (int kf = 0; kf < 2; ++kf)
      a[mi][kf] = read_frag(At, wm * 128 + (mlo + mi) * 16 + l16, kf, lhi);
}

template<int NLO>
__device__ __forceinline__ void ldb2(bf16x8 (&b)[4][2], const ushort_t* Btile,
                                     int wn, int l16, int lhi) {
#pragma unroll
  for (int ni = 0; ni < 2; ++ni)
#pragma unroll
    for (int kf = 0; kf < 2; ++kf)
      b[NLO + ni][kf] = read_frag(Btile, wn * 64 + (NLO + ni) * 16 + l16, kf, lhi);
}

template<int MLO, int NLO>
__device__ __forceinline__ void quad(f32x4 (&acc)[8][4], const bf16x8 (&a)[4][2],
                                     const bf16x8 (&b)[4][2]) {
  __builtin_amdgcn_s_setprio(1);
#pragma unroll
  for (int kf = 0; kf < 2; ++kf)
#pragma unroll
    for (int mi = 0; mi < 4; ++mi)
#pragma unroll
      for (int ni = 0; ni < 2; ++ni)
        acc[MLO + mi][NLO + ni] = __builtin_amdgcn_mfma_f32_16x16x32_bf16(
            a[mi][kf], b[NLO + ni][kf], acc[MLO + mi][NLO + ni], 0, 0, 0);
  __builtin_amdgcn_s_setprio(0);
}

__global__ __launch_bounds__(512, 2) void gemm256_qkv(
    const ushort_t* __restrict__ A, const ushort_t* __restrict__ Bt,
    const float* __restrict__ bias,
    ushort_t* __restrict__ Cq, ushort_t* __restrict__ Ck, ushort_t* __restrict__ Cv,
    int K, float qscale, int nbx)
{
  __shared__ ushort_t As[2][256 * 64];
  __shared__ ushort_t Bs[2][256 * 64];
  const int tid = threadIdx.x;
  const int w = tid >> 6, l = tid & 63;
  const int wm = w >> 2, wn = w & 3;          // 2 x 4 waves
  const int l16 = l & 15, lhi = l >> 4;

  // bijective XCD swizzle (gridDim.x % 8 == 0), m-major tiles
  const int nwg = (int)gridDim.x;
  const int cpx = nwg >> 3;
  const int lt = ((int)blockIdx.x & 7) * cpx + ((int)blockIdx.x >> 3);
  const int bm = (lt / nbx) * 256;
  const int bn = (lt % nbx) * 256;

  const ushort_t* Ag = A + (size_t)bm * K;
  const ushort_t* Bg = Bt + (size_t)bn * K;

  auto STAGE = [&](int tt, int hh) {
    const int kt = tt * 64;
    if (hh < 2)
      stage_half(Ag + (size_t)(hh * 128) * K + kt, K, &As[tt & 1][hh * 128 * 64], tid);
    else
      stage_half(Bg + (size_t)((hh - 2) * 128) * K + kt, K, &Bs[tt & 1][(hh - 2) * 128 * 64], tid);
  };

  f32x4 acc[8][4] = {};
  bf16x8 a[4][2], b[4][2];

  const int NT = K >> 6;   // 16 K-tiles

  // prologue: T0 fully -> buf0; T1 halves {B-h0, A-h0} -> buf1
  STAGE(0, 0); STAGE(0, 1); STAGE(0, 2); STAGE(0, 3);
  STAGE(1, 2); STAGE(1, 0);
  waitvm4();                       // forces T0 landed, leaves T1's two halves in flight
  __builtin_amdgcn_s_barrier();

  for (int t = 0; t < NT; t += 2) {
    const bool s2 = (t + 2 < NT), s3 = (t + 3 < NT);
    const ushort_t* A0 = &As[0][0]; const ushort_t* B0 = &Bs[0][0];
    const ushort_t* A1 = &As[1][0]; const ushort_t* B1 = &Bs[1][0];

    // ---- tile t (buf0) ----
    // P1
    lda4(a, A0, 0, wm, l16, lhi); ldb2<0>(b, B0, wn, l16, lhi);
    STAGE(t + 1, 3);
    __builtin_amdgcn_s_barrier(); lgkm0_fence();
    quad<0, 0>(acc, a, b);
    __builtin_amdgcn_s_barrier();
    // P2
    ldb2<2>(b, B0, wn, l16, lhi);
    STAGE(t + 1, 1);
    __builtin_amdgcn_s_barrier(); lgkm0_fence();
    quad<0, 2>(acc, a, b);
    __builtin_amdgcn_s_barrier();
    // P3
    lda4(a, A0, 4, wm, l16, lhi);
    if (s2) STAGE(t + 2, 2);
    __builtin_amdgcn_s_barrier(); lgkm0_fence();
    quad<4, 0>(acc, a, b);
    __builtin_amdgcn_s_barrier();
    // P4
    if (s2) { STAGE(t + 2, 0); waitvm4(); } else { waitvm0(); }
    __builtin_amdgcn_s_barrier();
    quad<4, 2>(acc, a, b);
    __builtin_amdgcn_s_barrier();

    // ---- tile t+1 (buf1) ----
    // P5
    lda4(a, A1, 0, wm, l16, lhi); ldb2<0>(b, B1, wn, l16, lhi);
    if (s2) STAGE(t + 2, 3);
    __builtin_amdgcn_s_barrier(); lgkm0_fence();
    quad<0, 0>(acc, a, b);
    __builtin_amdgcn_s_barrier();
    // P6
    ldb2<2>(b, B1, wn, l16, lhi);
    if (s2) STAGE(t + 2, 1);
    __builtin_amdgcn_s_barrier(); lgkm0_fence();
    quad<0, 2>(acc, a, b);
    __builtin_amdgcn_s_barrier();
    // P7
    lda4(a, A1, 4, wm, l16, lhi);
    if (s3) STAGE(t + 3, 2);
    __builtin_amdgcn_s_barrier(); lgkm0_fence();
    quad<4, 0>(acc, a, b);
    __builtin_amdgcn_s_barrier();
    // P8
    if (s3) { STAGE(t + 3, 0); waitvm4(); } else if (s2) { waitvm0(); }
    __builtin_amdgcn_s_barrier();
    quad<4, 2>(acc, a, b);
    __builtin_amdgcn_s_barrier();
  }

  // epilogue: bias + scatter Q/K [BH][S][D], V [BH][D][S]
#pragma unroll
  for (int mf = 0; mf < 8; ++mf) {
#pragma unroll
    for (int nf = 0; nf < 4; ++nf) {
      const int col = bn + wn * 64 + nf * 16 + l16;
      const float bv = bias[col];
      const int region = col >> 10;
      const int hcol = col & 1023;
      const int h_ = hcol >> 6, d_ = hcol & 63;
#pragma unroll
      for (int r = 0; r < 4; ++r) {
        const int row = bm + wm * 128 + mf * 16 + lhi * 4 + r;
        float v = acc[mf][nf][r] + bv;
        const int b_ = row >> 10, s_ = row & 1023;
        if (region == 2) {
          Cv[((size_t)(b_ * 16 + h_) * 64 + d_) * 1024 + s_] = f2bf(v);
        } else {
          ushort_t* base = (region == 0) ? Cq : Ck;
          if (region == 0) v *= qscale;
          base[((size_t)(b_ * 16 + h_) * 1024 + s_) * 64 + d_] = f2bf(v);
        }
      }
    }
  }
}

// ---------------- 128x128 GEMM (proj): C[M,N] = A[M,K]*Bt[N,K]^T + bias, fp32 out ----------------
__global__ __launch_bounds__(256, 2) void gemm_bt(
    const ushort_t* __restrict__ A, const ushort_t* __restrict__ Bt,
    const float* __restrict__ bias, float* __restrict__ Cf,
    int M, int N, int K)
{
  __shared__ ushort_t As[128 * 64];
  __shared__ ushort_t Bs[128 * 64];
  const int tid = threadIdx.x;
  const int w = tid >> 6, l = tid & 63;
  const int bm = blockIdx.y * 128, bn = blockIdx.x * 128;
  const int lr = l >> 3, lp = l & 7;
  const int l16 = l & 15, lhi = l >> 4;
  const int wm = (w >> 1) * 64, wn = (w & 1) * 64;

  f32x4 acc[4][4] = {};

  for (int kt = 0; kt < K; kt += 64) {
#pragma unroll
    for (int i = 0; i < 4; ++i) {
      const int ci = i * 4 + w;
      const int row = ci * 8 + lr;
      const int sc = (lp ^ (row & 7)) * 8;
      gload_lds16(A + (size_t)(bm + row) * K + kt + sc, &As[ci * 512]);
      gload_lds16(Bt + (size_t)(bn + row) * K + kt + sc, &Bs[ci * 512]);
    }
    __syncthreads();

    bf16x8 af[4][2], bfr[4][2];
#pragma unroll
    for (int mf = 0; mf < 4; ++mf) {
      const int row = wm + mf * 16 + l16;
#pragma unroll
      for (int kf = 0; kf < 2; ++kf) {
        const int ch = (lhi + kf * 4) ^ (row & 7);
        af[mf][kf] = *(const bf16x8*)((const char*)&As[row * 64] + ch * 16);
      }
    }
#pragma unroll
    for (int nf = 0; nf < 4; ++nf) {
      const int row = wn + nf * 16 + l16;
#pragma unroll
      for (int kf = 0; kf < 2; ++kf) {
        const int ch = (lhi + kf * 4) ^ (row & 7);
        bfr[nf][kf] = *(const bf16x8*)((const char*)&Bs[row * 64] + ch * 16);
      }
    }
#pragma unroll
    for (int kf = 0; kf < 2; ++kf)
#pragma unroll
      for (int mf = 0; mf < 4; ++mf)
#pragma unroll
        for (int nf = 0; nf < 4; ++nf)
          acc[mf][nf] = __builtin_amdgcn_mfma_f32_16x16x32_bf16(
              af[mf][kf], bfr[nf][kf], acc[mf][nf], 0, 0, 0);
    __syncthreads();
  }

#pragma unroll
  for (int mf = 0; mf < 4; ++mf) {
#pragma unroll
    for (int nf = 0; nf < 4; ++nf) {
      const int col = bn + wn + nf * 16 + l16;
      const float bv = bias[col];
#pragma unroll
      for (int r = 0; r < 4; ++r) {
        const int row = bm + wm + mf * 16 + lhi * 4 + r;
        Cf[(size_t)row * N + col] = acc[mf][nf][r] + bv;
      }
    }
  }
}

// ---------------- causal flash attention (swapped-operand, paired q-tiles) ----------------
__global__ __launch_bounds__(256, 2) void attn_kernel(
    const ushort_t* __restrict__ Q, const ushort_t* __restrict__ Kk,
    const ushort_t* __restrict__ Vt, ushort_t* __restrict__ O)
{
  __shared__ ushort_t Pl[8][32 * 68];  // [wave*2+half][q][64 kv + 4 pad] (136 B rows)
  const int tid = threadIdx.x;
  const int w = tid >> 6, l = tid & 63;
  const int l16 = l & 15, lhi = l >> 4;

  const int bid = blockIdx.x;
  const int bh = ((bid >> 5) << 3) | (bid & 7);   // head 0..127
  const int p  = (bid >> 3) & 3;                  // pair 0..3
  const int qtH = 7 - p, qtL = p;
  const int qbH = qtH * 128 + w * 32;
  const int qbL = qtL * 128 + w * 32;
  const int ntH = (qbH >> 6) + 1;
  const int ntL = (qbL >> 6) + 1;
  const size_t hb = (size_t)bh * (1024 * 64);
  const int b_ = bh >> 4, h_ = bh & 15;

  bf16x8 qfH[2][2], qfL[2][2];
#pragma unroll
  for (int mf = 0; mf < 2; ++mf)
#pragma unroll
    for (int kf = 0; kf < 2; ++kf) {
      qfH[mf][kf] = *(const bf16x8*)(Q + hb + (size_t)(qbH + mf * 16 + l16) * 64 + kf * 32 + lhi * 8);
      qfL[mf][kf] = *(const bf16x8*)(Q + hb + (size_t)(qbL + mf * 16 + l16) * 64 + kf * 32 + lhi * 8);
    }

  f32x4 oH[2][4] = {}, oL[2][4] = {};
  float mH[2] = {-1e30f, -1e30f}, lsH[2] = {0.0f, 0.0f};
  float mL[2] = {-1e30f, -1e30f}, lsL[2] = {0.0f, 0.0f};
  char* const pbH = (char*)&Pl[w * 2 + 0][0];
  char* const pbL = (char*)&Pl[w * 2 + 1][0];

  for (int t = 0; t < ntH; ++t) {
    const int kv0 = t * 64;

    bf16x8 kb[4][2], vb[4][2];
#pragma unroll
    for (int nf = 0; nf < 4; ++nf)
#pragma unroll
      for (int kf = 0; kf < 2; ++kf) {
        kb[nf][kf] = *(const bf16x8*)(Kk + hb + (size_t)(kv0 + nf * 16 + l16) * 64 + kf * 32 + lhi * 8);
        vb[nf][kf] = *(const bf16x8*)(Vt + hb + (size_t)(nf * 16 + l16) * 1024 + kv0 + kf * 32 + lhi * 8);
      }

    auto half = [&](const bf16x8 (&qf)[2][2], f32x4 (&o)[2][4],
                    float (&m_run)[2], float (&l_run)[2],
                    const int qbase, char* const pbase) {
      f32x4 s[2][4] = {};
#pragma unroll
      for (int nf = 0; nf < 4; ++nf)
#pragma unroll
        for (int kf = 0; kf < 2; ++kf)
#pragma unroll
          for (int mf = 0; mf < 2; ++mf)
            s[mf][nf] = __builtin_amdgcn_mfma_f32_16x16x32_bf16(kb[nf][kf], qf[mf][kf], s[mf][nf], 0, 0, 0);

      if (kv0 + 63 > qbase) {
#pragma unroll
        for (int mf = 0; mf < 2; ++mf) {
          const int q = qbase + mf * 16 + l16;
#pragma unroll
          for (int nf = 0; nf < 4; ++nf)
#pragma unroll
            for (int r = 0; r < 4; ++r) {
              const int kv = kv0 + nf * 16 + lhi * 4 + r;
              if (kv > q) s[mf][nf][r] = -1e30f;
            }
        }
      }

#pragma unroll
      for (int mf = 0; mf < 2; ++mf) {
        float lmax = -1e30f;
#pragma unroll
        for (int nf = 0; nf < 4; ++nf)
#pragma unroll
          for (int r = 0; r < 4; ++r) lmax = fmaxf(lmax, s[mf][nf][r]);
        lmax = fmaxf(lmax, __shfl_xor(lmax, 16));
        lmax = fmaxf(lmax, __shfl_xor(lmax, 32));
        const float mnew = fmaxf(m_run[mf], lmax);
        const float corr = exp2f(m_run[mf] - mnew);
        float psum = 0.0f;
#pragma unroll
        for (int nf = 0; nf < 4; ++nf)
#pragma unroll
          for (int r = 0; r < 4; ++r) {
            const float pv = exp2f(s[mf][nf][r] - mnew);
            s[mf][nf][r] = pv;
            psum += pv;
          }
        psum += __shfl_xor(psum, 16);
        psum += __shfl_xor(psum, 32);
        l_run[mf] = l_run[mf] * corr + psum;
        m_run[mf] = mnew;
#pragma unroll
        for (int nf = 0; nf < 4; ++nf) o[mf][nf] *= corr;

        const int q = mf * 16 + l16;
#pragma unroll
        for (int nf = 0; nf < 4; ++nf) {
          const uint32_t u0 = cvt_pk_bf16(s[mf][nf][0], s[mf][nf][1]);
          const uint32_t u1 = cvt_pk_bf16(s[mf][nf][2], s[mf][nf][3]);
          *(uint2*)(pbase + q * 136 + nf * 32 + lhi * 8) = make_uint2(u0, u1);
        }
      }

#pragma unroll
      for (int mf = 0; mf < 2; ++mf) {
        const int q = mf * 16 + l16;
#pragma unroll
        for (int kf = 0; kf < 2; ++kf) {
          const bf16x8 pb = *(const bf16x8*)(pbase + q * 136 + kf * 64 + lhi * 16);
#pragma unroll
          for (int nf = 0; nf < 4; ++nf)
            o[mf][nf] = __builtin_amdgcn_mfma_f32_16x16x32_bf16(vb[nf][kf], pb, o[mf][nf], 0, 0, 0);
        }
      }
    };

    half(qfH, oH, mH, lsH, qbH, pbH);
    if (t < ntL) half(qfL, oL, mL, lsL, qbL, pbL);
  }

  auto epi = [&](f32x4 (&o)[2][4], float (&l_run)[2], const int qbase) {
#pragma unroll
    for (int mf = 0; mf < 2; ++mf) {
      const float inv = 1.0f / l_run[mf];
      const int qrow = qbase + mf * 16 + l16;
      const size_t rb = ((size_t)(b_ * 1024 + qrow)) * 1024 + h_ * 64;
#pragma unroll
      for (int nf = 0; nf < 4; ++nf) {
        const uint32_t u0 = cvt_pk_bf16(o[mf][nf][0] * inv, o[mf][nf][1] * inv);
        const uint32_t u1 = cvt_pk_bf16(o[mf][nf][2] * inv, o[mf][nf][3] * inv);
        *(uint2*)(O + rb + nf * 16 + lhi * 4) = make_uint2(u0, u1);
      }
    }
  };
  epi(oH, lsH, qbH);
  epi(oL, lsL, qbL);
}

extern "C" void kernel_launch(void* const* d_in, const int* in_sizes, int n_in,
                              void* d_out, int out_size, void* d_ws, size_t ws_size,
                              hipStream_t stream) {
  const float* x      = (const float*)d_in[0];
  const float* W_attn = (const float*)d_in[1];
  const float* b_attn = (const float*)d_in[2];
  const float* W_proj = (const float*)d_in[3];
  const float* b_proj = (const float*)d_in[4];
  float* out = (float*)d_out;

  const int M = 8192;       // B*S
  const int E = 1024, N3 = 3072;
  const size_t T = (size_t)M * E;

  char* p = (char*)d_ws;
  ushort_t* xb  = (ushort_t*)p; p += T * 2;              // x bf16; reused as attn_out
  ushort_t* Wab = (ushort_t*)p; p += (size_t)N3 * E * 2; // W_attn^T bf16 [3072][1024]
  ushort_t* Wpb = (ushort_t*)p; p += (size_t)E * E * 2;  // W_proj^T bf16 [1024][1024]
  ushort_t* Qb  = (ushort_t*)p; p += T * 2;              // [BH][S][D]
  ushort_t* Kb  = (ushort_t*)p; p += T * 2;              // [BH][S][D]
  ushort_t* Vtb = (ushort_t*)p; p += T * 2;              // [BH][D][S]

  const float qscale = 0.125f * 1.4426950408889634f;     // 1/sqrt(D) * log2(e)

  cast_x<<<dim3((int)(T / 1024)), dim3(256), 0, stream>>>(x, xb, (int)T);
  transpose_cast<<<dim3(N3 / 32, E / 32), dim3(256), 0, stream>>>(W_attn, Wab, E, N3);
  transpose_cast<<<dim3(E / 32, E / 32), dim3(256), 0, stream>>>(W_proj, Wpb, E, E);
  gemm256_qkv<<<dim3((M / 256) * (N3 / 256)), dim3(512), 0, stream>>>(
      xb, Wab, b_attn, Qb, Kb, Vtb, E, qscale, N3 / 256);
  attn_kernel<<<dim3(512), dim3(256), 0, stream>>>(Qb, Kb, Vtb, xb);
  gemm_bt<<<dim3(E / 128, M / 128), dim3(256), 0, stream>>>(
      xb, Wpb, b_proj, out, M, E, E);
}

// Round 6
// 208.032 us; speedup vs baseline: 1.0339x; 1.0339x over previous
//
#include <hip/hip_runtime.h>
#include <hip/hip_bf16.h>
#include <stdint.h>

typedef unsigned short ushort_t;
typedef __attribute__((ext_vector_type(8))) __bf16 bf16x8;
typedef __attribute__((ext_vector_type(4))) float f32x4;

typedef const __attribute__((address_space(1))) uint32_t* gptr_t;
typedef __attribute__((address_space(3))) uint32_t* lptr_t;

__device__ __forceinline__ ushort_t f2bf(float f) {
  union { float f; uint32_t u; } x; x.f = f;
  uint32_t u = x.u;
  uint32_t r = (u + 0x7fffu + ((u >> 16) & 1u)) >> 16;
  return (ushort_t)r;
}

__device__ __forceinline__ uint32_t cvt_pk_bf16(float lo, float hi) {
  uint32_t r;
  asm("v_cvt_pk_bf16_f32 %0, %1, %2" : "=v"(r) : "v"(lo), "v"(hi));
  return r;
}

__device__ __forceinline__ void gload_lds16(const void* g, void* l) {
  __builtin_amdgcn_global_load_lds((gptr_t)g, (lptr_t)l, 16, 0, 0);
}

__device__ __forceinline__ void lgkm0_fence() {
  asm volatile("s_waitcnt lgkmcnt(0)" ::: "memory");
  __builtin_amdgcn_sched_barrier(0);
}
__device__ __forceinline__ void waitvm4() { asm volatile("s_waitcnt vmcnt(4)" ::: "memory"); }
__device__ __forceinline__ void waitvm0() { asm volatile("s_waitcnt vmcnt(0)" ::: "memory"); }

// ---------------- cast x (fp32 -> bf16) ----------------
__global__ void cast_x(const float* __restrict__ in, ushort_t* __restrict__ out, int n) {
  const int idx = (blockIdx.x * 256 + threadIdx.x) * 4;
  if (idx < n) {
    const float4 v = *(const float4*)(in + idx);
    ushort4 o;
    o.x = f2bf(v.x); o.y = f2bf(v.y); o.z = f2bf(v.z); o.w = f2bf(v.w);
    *(ushort4*)(out + idx) = o;
  }
}

// ---------------- transpose + cast weights: in[K][N] fp32 -> out[N][K] bf16 ----------------
__global__ void transpose_cast(const float* __restrict__ in, ushort_t* __restrict__ out, int K, int N) {
  __shared__ ushort_t t[32][33];
  const int n0 = blockIdx.x * 32, k0 = blockIdx.y * 32;
  const int c = threadIdx.x & 31, r0 = threadIdx.x >> 5;
#pragma unroll
  for (int i = 0; i < 4; ++i) {
    const int r = r0 + i * 8;
    t[r][c] = f2bf(in[(size_t)(k0 + r) * N + n0 + c]);
  }
  __syncthreads();
#pragma unroll
  for (int i = 0; i < 4; ++i) {
    const int r = r0 + i * 8;
    out[(size_t)(n0 + r) * K + k0 + c] = t[c][r];
  }
}

// ================= 256x256 8-phase GEMM (T2+T3+T4+T5), QKV scatter epilogue =================
// A[M,K] * Bt[N,K]^T + bias -> Q,K -> [BH][S][D] (Q pre-scaled), V -> [BH][D][S].
// 3-bit XOR swizzle (conflict-free ds_read_b128): read byte ^= (row&7)<<4, matched by
// pre-swizzled global source chunk chs = ch ^ (row&7) on stage (linear gload_lds dest).
// Counted vmcnt(4) at phases 4/8 only; raw s_barrier (no __syncthreads -> no vmcnt drain).

__device__ __forceinline__ void stage_half(const ushort_t* g, int ldk,
                                           ushort_t* lds, int tid) {
  const int r0 = tid >> 3;                       // 0..63
  const int ch = tid & 7;                        // 16B chunk in 128B row
  const int chs = ch ^ (r0 & 7);                 // pre-swizzle source chunk by row&7
#pragma unroll
  for (int j = 0; j < 2; ++j) {
    const int row = j * 64 + r0;                 // row&7 == r0&7
    gload_lds16(g + (size_t)row * ldk + chs * 8, lds + row * 64 + ch * 8);
  }
}

__device__ __forceinline__ bf16x8 read_frag(const ushort_t* tile, int row, int kf, int lhi) {
  const int bc = (kf * 64 + lhi * 16) ^ ((row & 7) << 4);
  return *(const bf16x8*)((const char*)(tile + row * 64) + bc);
}

__device__ __forceinline__ void lda4(bf16x8 (&a)[4][2], const ushort_t* At,
                                     int mlo, int wm, int l16, int lhi) {
#pragma unroll
  for (int mi = 0; mi < 4; ++mi)
#pragma unroll
    for (int kf = 0; kf < 2; ++kf)
      a[mi][kf] = read_frag(At, wm * 128 + (mlo + mi) * 16 + l16, kf, lhi);
}

template<int NLO>
__device__ __forceinline__ void ldb2(bf16x8 (&b)[4][2], const ushort_t* Btile,
                                     int wn, int l16, int lhi) {
#pragma unroll
  for (int ni = 0; ni < 2; ++ni)
#pragma unroll
    for (int kf = 0; kf < 2; ++kf)
      b[NLO + ni][kf] = read_frag(Btile, wn * 64 + (NLO + ni) * 16 + l16, kf, lhi);
}

template<int MLO, int NLO>
__device__ __forceinline__ void quad(f32x4 (&acc)[8][4], const bf16x8 (&a)[4][2],
                                     const bf16x8 (&b)[4][2]) {
  __builtin_amdgcn_s_setprio(1);
#pragma unroll
  for (int kf = 0; kf < 2; ++kf)
#pragma unroll
    for (int mi = 0; mi < 4; ++mi)
#pragma unroll
      for (int ni = 0; ni < 2; ++ni)
        acc[MLO + mi][NLO + ni] = __builtin_amdgcn_mfma_f32_16x16x32_bf16(
            a[mi][kf], b[NLO + ni][kf], acc[MLO + mi][NLO + ni], 0, 0, 0);
  __builtin_amdgcn_s_setprio(0);
}

__global__ __launch_bounds__(512, 2) void gemm256_qkv(
    const ushort_t* __restrict__ A, const ushort_t* __restrict__ Bt,
    const float* __restrict__ bias,
    ushort_t* __restrict__ Cq, ushort_t* __restrict__ Ck, ushort_t* __restrict__ Cv,
    int K, float qscale, int nbx)
{
  __shared__ ushort_t As[2][256 * 64];
  __shared__ ushort_t Bs[2][256 * 64];
  const int tid = threadIdx.x;
  const int w = tid >> 6, l = tid & 63;
  const int wm = w >> 2, wn = w & 3;          // 2 x 4 waves
  const int l16 = l & 15, lhi = l >> 4;

  // bijective XCD swizzle (gridDim.x % 8 == 0), m-major tiles
  const int nwg = (int)gridDim.x;
  const int cpx = nwg >> 3;
  const int lt = ((int)blockIdx.x & 7) * cpx + ((int)blockIdx.x >> 3);
  const int bm = (lt / nbx) * 256;
  const int bn = (lt % nbx) * 256;

  const ushort_t* Ag = A + (size_t)bm * K;
  const ushort_t* Bg = Bt + (size_t)bn * K;

  auto STAGE = [&](int tt, int hh) {
    const int kt = tt * 64;
    if (hh < 2)
      stage_half(Ag + (size_t)(hh * 128) * K + kt, K, &As[tt & 1][hh * 128 * 64], tid);
    else
      stage_half(Bg + (size_t)((hh - 2) * 128) * K + kt, K, &Bs[tt & 1][(hh - 2) * 128 * 64], tid);
  };

  f32x4 acc[8][4] = {};
  bf16x8 a[4][2], b[4][2];

  const int NT = K >> 6;   // 16 K-tiles

  // prologue: T0 fully -> buf0; T1 halves {B-h0, A-h0} -> buf1
  STAGE(0, 0); STAGE(0, 1); STAGE(0, 2); STAGE(0, 3);
  STAGE(1, 2); STAGE(1, 0);
  waitvm4();                       // forces T0 landed, leaves T1's two halves in flight
  __builtin_amdgcn_s_barrier();

  for (int t = 0; t < NT; t += 2) {
    const bool s2 = (t + 2 < NT), s3 = (t + 3 < NT);
    const ushort_t* A0 = &As[0][0]; const ushort_t* B0 = &Bs[0][0];
    const ushort_t* A1 = &As[1][0]; const ushort_t* B1 = &Bs[1][0];

    // ---- tile t (buf0) ----
    // P1
    lda4(a, A0, 0, wm, l16, lhi); ldb2<0>(b, B0, wn, l16, lhi);
    STAGE(t + 1, 3);
    __builtin_amdgcn_s_barrier(); lgkm0_fence();
    quad<0, 0>(acc, a, b);
    __builtin_amdgcn_s_barrier();
    // P2
    ldb2<2>(b, B0, wn, l16, lhi);
    STAGE(t + 1, 1);
    __builtin_amdgcn_s_barrier(); lgkm0_fence();
    quad<0, 2>(acc, a, b);
    __builtin_amdgcn_s_barrier();
    // P3
    lda4(a, A0, 4, wm, l16, lhi);
    if (s2) STAGE(t + 2, 2);
    __builtin_amdgcn_s_barrier(); lgkm0_fence();
    quad<4, 0>(acc, a, b);
    __builtin_amdgcn_s_barrier();
    // P4
    if (s2) { STAGE(t + 2, 0); waitvm4(); } else { waitvm0(); }
    __builtin_amdgcn_s_barrier();
    quad<4, 2>(acc, a, b);
    __builtin_amdgcn_s_barrier();

    // ---- tile t+1 (buf1) ----
    // P5
    lda4(a, A1, 0, wm, l16, lhi); ldb2<0>(b, B1, wn, l16, lhi);
    if (s2) STAGE(t + 2, 3);
    __builtin_amdgcn_s_barrier(); lgkm0_fence();
    quad<0, 0>(acc, a, b);
    __builtin_amdgcn_s_barrier();
    // P6
    ldb2<2>(b, B1, wn, l16, lhi);
    if (s2) STAGE(t + 2, 1);
    __builtin_amdgcn_s_barrier(); lgkm0_fence();
    quad<0, 2>(acc, a, b);
    __builtin_amdgcn_s_barrier();
    // P7
    lda4(a, A1, 4, wm, l16, lhi);
    if (s3) STAGE(t + 3, 2);
    __builtin_amdgcn_s_barrier(); lgkm0_fence();
    quad<4, 0>(acc, a, b);
    __builtin_amdgcn_s_barrier();
    // P8
    if (s3) { STAGE(t + 3, 0); waitvm4(); } else if (s2) { waitvm0(); }
    __builtin_amdgcn_s_barrier();
    quad<4, 2>(acc, a, b);
    __builtin_amdgcn_s_barrier();
  }

  // epilogue: bias + scatter Q/K [BH][S][D], V [BH][D][S]
#pragma unroll
  for (int mf = 0; mf < 8; ++mf) {
#pragma unroll
    for (int nf = 0; nf < 4; ++nf) {
      const int col = bn + wn * 64 + nf * 16 + l16;
      const float bv = bias[col];
      const int region = col >> 10;
      const int hcol = col & 1023;
      const int h_ = hcol >> 6, d_ = hcol & 63;
#pragma unroll
      for (int r = 0; r < 4; ++r) {
        const int row = bm + wm * 128 + mf * 16 + lhi * 4 + r;
        float v = acc[mf][nf][r] + bv;
        const int b_ = row >> 10, s_ = row & 1023;
        if (region == 2) {
          Cv[((size_t)(b_ * 16 + h_) * 64 + d_) * 1024 + s_] = f2bf(v);
        } else {
          ushort_t* base = (region == 0) ? Cq : Ck;
          if (region == 0) v *= qscale;
          base[((size_t)(b_ * 16 + h_) * 1024 + s_) * 64 + d_] = f2bf(v);
        }
      }
    }
  }
}

// ---------------- 128x128 GEMM (proj): C[M,N] = A[M,K]*Bt[N,K]^T + bias, fp32 out ----------------
__global__ __launch_bounds__(256, 2) void gemm_bt(
    const ushort_t* __restrict__ A, const ushort_t* __restrict__ Bt,
    const float* __restrict__ bias, float* __restrict__ Cf,
    int M, int N, int K)
{
  __shared__ ushort_t As[128 * 64];
  __shared__ ushort_t Bs[128 * 64];
  const int tid = threadIdx.x;
  const int w = tid >> 6, l = tid & 63;
  const int bm = blockIdx.y * 128, bn = blockIdx.x * 128;
  const int lr = l >> 3, lp = l & 7;
  const int l16 = l & 15, lhi = l >> 4;
  const int wm = (w >> 1) * 64, wn = (w & 1) * 64;

  f32x4 acc[4][4] = {};

  for (int kt = 0; kt < K; kt += 64) {
#pragma unroll
    for (int i = 0; i < 4; ++i) {
      const int ci = i * 4 + w;
      const int row = ci * 8 + lr;
      const int sc = (lp ^ (row & 7)) * 8;
      gload_lds16(A + (size_t)(bm + row) * K + kt + sc, &As[ci * 512]);
      gload_lds16(Bt + (size_t)(bn + row) * K + kt + sc, &Bs[ci * 512]);
    }
    __syncthreads();

    bf16x8 af[4][2], bfr[4][2];
#pragma unroll
    for (int mf = 0; mf < 4; ++mf) {
      const int row = wm + mf * 16 + l16;
#pragma unroll
      for (int kf = 0; kf < 2; ++kf) {
        const int ch = (lhi + kf * 4) ^ (row & 7);
        af[mf][kf] = *(const bf16x8*)((const char*)&As[row * 64] + ch * 16);
      }
    }
#pragma unroll
    for (int nf = 0; nf < 4; ++nf) {
      const int row = wn + nf * 16 + l16;
#pragma unroll
      for (int kf = 0; kf < 2; ++kf) {
        const int ch = (lhi + kf * 4) ^ (row & 7);
        bfr[nf][kf] = *(const bf16x8*)((const char*)&Bs[row * 64] + ch * 16);
      }
    }
#pragma unroll
    for (int kf = 0; kf < 2; ++kf)
#pragma unroll
      for (int mf = 0; mf < 4; ++mf)
#pragma unroll
        for (int nf = 0; nf < 4; ++nf)
          acc[mf][nf] = __builtin_amdgcn_mfma_f32_16x16x32_bf16(
              af[mf][kf], bfr[nf][kf], acc[mf][nf], 0, 0, 0);
    __syncthreads();
  }

#pragma unroll
  for (int mf = 0; mf < 4; ++mf) {
#pragma unroll
    for (int nf = 0; nf < 4; ++nf) {
      const int col = bn + wn + nf * 16 + l16;
      const float bv = bias[col];
#pragma unroll
      for (int r = 0; r < 4; ++r) {
        const int row = bm + wm + mf * 16 + lhi * 4 + r;
        Cf[(size_t)row * N + col] = acc[mf][nf][r] + bv;
      }
    }
  }
}

// ---------------- causal flash attention (swapped-operand, paired q-tiles) ----------------
__global__ __launch_bounds__(256, 2) void attn_kernel(
    const ushort_t* __restrict__ Q, const ushort_t* __restrict__ Kk,
    const ushort_t* __restrict__ Vt, ushort_t* __restrict__ O)
{
  __shared__ ushort_t Pl[8][32 * 68];  // [wave*2+half][q][64 kv + 4 pad] (136 B rows)
  const int tid = threadIdx.x;
  const int w = tid >> 6, l = tid & 63;
  const int l16 = l & 15, lhi = l >> 4;

  const int bid = blockIdx.x;
  const int bh = ((bid >> 5) << 3) | (bid & 7);   // head 0..127
  const int p  = (bid >> 3) & 3;                  // pair 0..3
  const int qtH = 7 - p, qtL = p;
  const int qbH = qtH * 128 + w * 32;
  const int qbL = qtL * 128 + w * 32;
  const int ntH = (qbH >> 6) + 1;
  const int ntL = (qbL >> 6) + 1;
  const size_t hb = (size_t)bh * (1024 * 64);
  const int b_ = bh >> 4, h_ = bh & 15;

  bf16x8 qfH[2][2], qfL[2][2];
#pragma unroll
  for (int mf = 0; mf < 2; ++mf)
#pragma unroll
    for (int kf = 0; kf < 2; ++kf) {
      qfH[mf][kf] = *(const bf16x8*)(Q + hb + (size_t)(qbH + mf * 16 + l16) * 64 + kf * 32 + lhi * 8);
      qfL[mf][kf] = *(const bf16x8*)(Q + hb + (size_t)(qbL + mf * 16 + l16) * 64 + kf * 32 + lhi * 8);
    }

  f32x4 oH[2][4] = {}, oL[2][4] = {};
  float mH[2] = {-1e30f, -1e30f}, lsH[2] = {0.0f, 0.0f};
  float mL[2] = {-1e30f, -1e30f}, lsL[2] = {0.0f, 0.0f};
  char* const pbH = (char*)&Pl[w * 2 + 0][0];
  char* const pbL = (char*)&Pl[w * 2 + 1][0];

  for (int t = 0; t < ntH; ++t) {
    const int kv0 = t * 64;

    bf16x8 kb[4][2], vb[4][2];
#pragma unroll
    for (int nf = 0; nf < 4; ++nf)
#pragma unroll
      for (int kf = 0; kf < 2; ++kf) {
        kb[nf][kf] = *(const bf16x8*)(Kk + hb + (size_t)(kv0 + nf * 16 + l16) * 64 + kf * 32 + lhi * 8);
        vb[nf][kf] = *(const bf16x8*)(Vt + hb + (size_t)(nf * 16 + l16) * 1024 + kv0 + kf * 32 + lhi * 8);
      }

    auto half = [&](const bf16x8 (&qf)[2][2], f32x4 (&o)[2][4],
                    float (&m_run)[2], float (&l_run)[2],
                    const int qbase, char* const pbase) {
      f32x4 s[2][4] = {};
#pragma unroll
      for (int nf = 0; nf < 4; ++nf)
#pragma unroll
        for (int kf = 0; kf < 2; ++kf)
#pragma unroll
          for (int mf = 0; mf < 2; ++mf)
            s[mf][nf] = __builtin_amdgcn_mfma_f32_16x16x32_bf16(kb[nf][kf], qf[mf][kf], s[mf][nf], 0, 0, 0);

      if (kv0 + 63 > qbase) {
#pragma unroll
        for (int mf = 0; mf < 2; ++mf) {
          const int q = qbase + mf * 16 + l16;
#pragma unroll
          for (int nf = 0; nf < 4; ++nf)
#pragma unroll
            for (int r = 0; r < 4; ++r) {
              const int kv = kv0 + nf * 16 + lhi * 4 + r;
              if (kv > q) s[mf][nf][r] = -1e30f;
            }
        }
      }

#pragma unroll
      for (int mf = 0; mf < 2; ++mf) {
        float lmax = -1e30f;
#pragma unroll
        for (int nf = 0; nf < 4; ++nf)
#pragma unroll
          for (int r = 0; r < 4; ++r) lmax = fmaxf(lmax, s[mf][nf][r]);
        lmax = fmaxf(lmax, __shfl_xor(lmax, 16));
        lmax = fmaxf(lmax, __shfl_xor(lmax, 32));
        const float mnew = fmaxf(m_run[mf], lmax);
        const float corr = exp2f(m_run[mf] - mnew);
        float psum = 0.0f;
#pragma unroll
        for (int nf = 0; nf < 4; ++nf)
#pragma unroll
          for (int r = 0; r < 4; ++r) {
            const float pv = exp2f(s[mf][nf][r] - mnew);
            s[mf][nf][r] = pv;
            psum += pv;
          }
        psum += __shfl_xor(psum, 16);
        psum += __shfl_xor(psum, 32);
        l_run[mf] = l_run[mf] * corr + psum;
        m_run[mf] = mnew;
#pragma unroll
        for (int nf = 0; nf < 4; ++nf) o[mf][nf] *= corr;

        const int q = mf * 16 + l16;
#pragma unroll
        for (int nf = 0; nf < 4; ++nf) {
          const uint32_t u0 = cvt_pk_bf16(s[mf][nf][0], s[mf][nf][1]);
          const uint32_t u1 = cvt_pk_bf16(s[mf][nf][2], s[mf][nf][3]);
          *(uint2*)(pbase + q * 136 + nf * 32 + lhi * 8) = make_uint2(u0, u1);
        }
      }

#pragma unroll
      for (int mf = 0; mf < 2; ++mf) {
        const int q = mf * 16 + l16;
#pragma unroll
        for (int kf = 0; kf < 2; ++kf) {
          const bf16x8 pb = *(const bf16x8*)(pbase + q * 136 + kf * 64 + lhi * 16);
#pragma unroll
          for (int nf = 0; nf < 4; ++nf)
            o[mf][nf] = __builtin_amdgcn_mfma_f32_16x16x32_bf16(vb[nf][kf], pb, o[mf][nf], 0, 0, 0);
        }
      }
    };

    half(qfH, oH, mH, lsH, qbH, pbH);
    if (t < ntL) half(qfL, oL, mL, lsL, qbL, pbL);
  }

  auto epi = [&](f32x4 (&o)[2][4], float (&l_run)[2], const int qbase) {
#pragma unroll
    for (int mf = 0; mf < 2; ++mf) {
      const float inv = 1.0f / l_run[mf];
      const int qrow = qbase + mf * 16 + l16;
      const size_t rb = ((size_t)(b_ * 1024 + qrow)) * 1024 + h_ * 64;
#pragma unroll
      for (int nf = 0; nf < 4; ++nf) {
        const uint32_t u0 = cvt_pk_bf16(o[mf][nf][0] * inv, o[mf][nf][1] * inv);
        const uint32_t u1 = cvt_pk_bf16(o[mf][nf][2] * inv, o[mf][nf][3] * inv);
        *(uint2*)(O + rb + nf * 16 + lhi * 4) = make_uint2(u0, u1);
      }
    }
  };
  epi(oH, lsH, qbH);
  epi(oL, lsL, qbL);
}

extern "C" void kernel_launch(void* const* d_in, const int* in_sizes, int n_in,
                              void* d_out, int out_size, void* d_ws, size_t ws_size,
                              hipStream_t stream) {
  const float* x      = (const float*)d_in[0];
  const float* W_attn = (const float*)d_in[1];
  const float* b_attn = (const float*)d_in[2];
  const float* W_proj = (const float*)d_in[3];
  const float* b_proj = (const float*)d_in[4];
  float* out = (float*)d_out;

  const int M = 8192;       // B*S
  const int E = 1024, N3 = 3072;
  const size_t T = (size_t)M * E;

  char* p = (char*)d_ws;
  ushort_t* xb  = (ushort_t*)p; p += T * 2;              // x bf16; reused as attn_out
  ushort_t* Wab = (ushort_t*)p; p += (size_t)N3 * E * 2; // W_attn^T bf16 [3072][1024]
  ushort_t* Wpb = (ushort_t*)p; p += (size_t)E * E * 2;  // W_proj^T bf16 [1024][1024]
  ushort_t* Qb  = (ushort_t*)p; p += T * 2;              // [BH][S][D]
  ushort_t* Kb  = (ushort_t*)p; p += T * 2;              // [BH][S][D]
  ushort_t* Vtb = (ushort_t*)p; p += T * 2;              // [BH][D][S]

  const float qscale = 0.125f * 1.4426950408889634f;     // 1/sqrt(D) * log2(e)

  cast_x<<<dim3((int)(T / 1024)), dim3(256), 0, stream>>>(x, xb, (int)T);
  transpose_cast<<<dim3(N3 / 32, E / 32), dim3(256), 0, stream>>>(W_attn, Wab, E, N3);
  transpose_cast<<<dim3(E / 32, E / 32), dim3(256), 0, stream>>>(W_proj, Wpb, E, E);
  gemm256_qkv<<<dim3((M / 256) * (N3 / 256)), dim3(512), 0, stream>>>(
      xb, Wab, b_attn, Qb, Kb, Vtb, E, qscale, N3 / 256);
  attn_kernel<<<dim3(512), dim3(256), 0, stream>>>(Qb, Kb, Vtb, xb);
  gemm_bt<<<dim3(E / 128, M / 128), dim3(256), 0, stream>>>(
      xb, Wpb, b_proj, out, M, E, E);
}

// Round 7
// 191.326 us; speedup vs baseline: 1.1242x; 1.0873x over previous
//
#include <hip/hip_runtime.h>
#include <hip/hip_bf16.h>
#include <stdint.h>

typedef unsigned short ushort_t;
typedef __attribute__((ext_vector_type(8))) __bf16 bf16x8;
typedef __attribute__((ext_vector_type(4))) float f32x4;

typedef const __attribute__((address_space(1))) uint32_t* gptr_t;
typedef __attribute__((address_space(3))) uint32_t* lptr_t;

__device__ __forceinline__ ushort_t f2bf(float f) {
  union { float f; uint32_t u; } x; x.f = f;
  uint32_t u = x.u;
  uint32_t r = (u + 0x7fffu + ((u >> 16) & 1u)) >> 16;
  return (ushort_t)r;
}

__device__ __forceinline__ uint32_t cvt_pk_bf16(float lo, float hi) {
  uint32_t r;
  asm("v_cvt_pk_bf16_f32 %0, %1, %2" : "=v"(r) : "v"(lo), "v"(hi));
  return r;
}

__device__ __forceinline__ void gload_lds16(const void* g, void* l) {
  __builtin_amdgcn_global_load_lds((gptr_t)g, (lptr_t)l, 16, 0, 0);
}

// ---------------- cast x (fp32 -> bf16) ----------------
__global__ void cast_x(const float* __restrict__ in, ushort_t* __restrict__ out, int n) {
  const int idx = (blockIdx.x * 256 + threadIdx.x) * 4;
  if (idx < n) {
    const float4 v = *(const float4*)(in + idx);
    ushort4 o;
    o.x = f2bf(v.x); o.y = f2bf(v.y); o.z = f2bf(v.z); o.w = f2bf(v.w);
    *(ushort4*)(out + idx) = o;
  }
}

// ---------------- transpose + cast weights: in[K][N] fp32 -> out[N][K] bf16 ----------------
__global__ void transpose_cast(const float* __restrict__ in, ushort_t* __restrict__ out, int K, int N) {
  __shared__ ushort_t t[32][33];
  const int n0 = blockIdx.x * 32, k0 = blockIdx.y * 32;
  const int c = threadIdx.x & 31, r0 = threadIdx.x >> 5;
#pragma unroll
  for (int i = 0; i < 4; ++i) {
    const int r = r0 + i * 8;
    t[r][c] = f2bf(in[(size_t)(k0 + r) * N + n0 + c]);
  }
  __syncthreads();
#pragma unroll
  for (int i = 0; i < 4; ++i) {
    const int r = r0 + i * 8;
    out[(size_t)(n0 + r) * K + k0 + c] = t[c][r];
  }
}

// ---------------- GEMM: C[M,N] = A[M,K] * Bt[N,K]^T + bias ----------------
// MODE 1: fp32 out to Cf.
// MODE 2: bf16 out scattered: Q,K -> [BH][S][D] (Q pre-scaled), V -> [BH][D][S].
template<int MODE>
__global__ __launch_bounds__(256, 4) void gemm_bt(
    const ushort_t* __restrict__ A, const ushort_t* __restrict__ Bt,
    const float* __restrict__ bias,
    ushort_t* __restrict__ Cq, ushort_t* __restrict__ Ck, ushort_t* __restrict__ Cv,
    float* __restrict__ Cf,
    int M, int N, int K, float qscale)
{
  __shared__ ushort_t As[128 * 64];
  __shared__ ushort_t Bs[128 * 64];
  const int tid = threadIdx.x;
  const int w = tid >> 6, l = tid & 63;
  const int bm = blockIdx.y * 128, bn = blockIdx.x * 128;
  const int lr = l >> 3, lp = l & 7;
  const int l16 = l & 15, lhi = l >> 4;
  const int wm = (w >> 1) * 64, wn = (w & 1) * 64;

  f32x4 acc[4][4] = {};

  for (int kt = 0; kt < K; kt += 64) {
#pragma unroll
    for (int i = 0; i < 4; ++i) {
      const int ci = i * 4 + w;
      const int row = ci * 8 + lr;
      const int sc = (lp ^ (row & 7)) * 8;
      gload_lds16(A + (size_t)(bm + row) * K + kt + sc, &As[ci * 512]);
      gload_lds16(Bt + (size_t)(bn + row) * K + kt + sc, &Bs[ci * 512]);
    }
    __syncthreads();

    bf16x8 af[4][2], bfr[4][2];
#pragma unroll
    for (int mf = 0; mf < 4; ++mf) {
      const int row = wm + mf * 16 + l16;
#pragma unroll
      for (int kf = 0; kf < 2; ++kf) {
        const int ch = (lhi + kf * 4) ^ (row & 7);
        af[mf][kf] = *(const bf16x8*)((const char*)&As[row * 64] + ch * 16);
      }
    }
#pragma unroll
    for (int nf = 0; nf < 4; ++nf) {
      const int row = wn + nf * 16 + l16;
#pragma unroll
      for (int kf = 0; kf < 2; ++kf) {
        const int ch = (lhi + kf * 4) ^ (row & 7);
        bfr[nf][kf] = *(const bf16x8*)((const char*)&Bs[row * 64] + ch * 16);
      }
    }
#pragma unroll
    for (int kf = 0; kf < 2; ++kf)
#pragma unroll
      for (int mf = 0; mf < 4; ++mf)
#pragma unroll
        for (int nf = 0; nf < 4; ++nf)
          acc[mf][nf] = __builtin_amdgcn_mfma_f32_16x16x32_bf16(
              af[mf][kf], bfr[nf][kf], acc[mf][nf], 0, 0, 0);
    __syncthreads();
  }

#pragma unroll
  for (int mf = 0; mf < 4; ++mf) {
#pragma unroll
    for (int nf = 0; nf < 4; ++nf) {
      const int col = bn + wn + nf * 16 + l16;
      const float bv = bias[col];
#pragma unroll
      for (int r = 0; r < 4; ++r) {
        const int row = bm + wm + mf * 16 + lhi * 4 + r;
        float v = acc[mf][nf][r] + bv;
        if constexpr (MODE == 1) {
          Cf[(size_t)row * N + col] = v;
        } else {
          const int region = col >> 10;
          const int hcol = col & 1023;
          const int b_ = row >> 10, s_ = row & 1023;
          const int h_ = hcol >> 6, d_ = hcol & 63;
          if (region == 2) {
            // V: write transposed [BH][D][S]
            Cv[((size_t)(b_ * 16 + h_) * 64 + d_) * 1024 + s_] = f2bf(v);
          } else {
            ushort_t* base = (region == 0) ? Cq : Ck;
            if (region == 0) v *= qscale;
            base[((size_t)(b_ * 16 + h_) * 1024 + s_) * 64 + d_] = f2bf(v);
          }
        }
      }
    }
  }
}

// ---------------- causal flash attention (swapped-operand, paired q-tiles) ----------------
__global__ __launch_bounds__(256, 2) void attn_kernel(
    const ushort_t* __restrict__ Q, const ushort_t* __restrict__ Kk,
    const ushort_t* __restrict__ Vt, ushort_t* __restrict__ O)
{
  __shared__ ushort_t Pl[8][32 * 68];  // [wave*2+half][q][64 kv + 4 pad] (136 B rows)
  const int tid = threadIdx.x;
  const int w = tid >> 6, l = tid & 63;
  const int l16 = l & 15, lhi = l >> 4;

  const int bid = blockIdx.x;
  const int bh = ((bid >> 5) << 3) | (bid & 7);   // head 0..127
  const int p  = (bid >> 3) & 3;                  // pair 0..3
  const int qtH = 7 - p, qtL = p;
  const int qbH = qtH * 128 + w * 32;
  const int qbL = qtL * 128 + w * 32;
  const int ntH = (qbH >> 6) + 1;
  const int ntL = (qbL >> 6) + 1;
  const size_t hb = (size_t)bh * (1024 * 64);
  const int b_ = bh >> 4, h_ = bh & 15;

  bf16x8 qfH[2][2], qfL[2][2];
#pragma unroll
  for (int mf = 0; mf < 2; ++mf)
#pragma unroll
    for (int kf = 0; kf < 2; ++kf) {
      qfH[mf][kf] = *(const bf16x8*)(Q + hb + (size_t)(qbH + mf * 16 + l16) * 64 + kf * 32 + lhi * 8);
      qfL[mf][kf] = *(const bf16x8*)(Q + hb + (size_t)(qbL + mf * 16 + l16) * 64 + kf * 32 + lhi * 8);
    }

  f32x4 oH[2][4] = {}, oL[2][4] = {};
  float mH[2] = {-1e30f, -1e30f}, lsH[2] = {0.0f, 0.0f};
  float mL[2] = {-1e30f, -1e30f}, lsL[2] = {0.0f, 0.0f};
  char* const pbH = (char*)&Pl[w * 2 + 0][0];
  char* const pbL = (char*)&Pl[w * 2 + 1][0];

  for (int t = 0; t < ntH; ++t) {
    const int kv0 = t * 64;

    bf16x8 kb[4][2], vb[4][2];
#pragma unroll
    for (int nf = 0; nf < 4; ++nf)
#pragma unroll
      for (int kf = 0; kf < 2; ++kf) {
        kb[nf][kf] = *(const bf16x8*)(Kk + hb + (size_t)(kv0 + nf * 16 + l16) * 64 + kf * 32 + lhi * 8);
        vb[nf][kf] = *(const bf16x8*)(Vt + hb + (size_t)(nf * 16 + l16) * 1024 + kv0 + kf * 32 + lhi * 8);
      }

    auto half = [&](const bf16x8 (&qf)[2][2], f32x4 (&o)[2][4],
                    float (&m_run)[2], float (&l_run)[2],
                    const int qbase, char* const pbase) {
      f32x4 s[2][4] = {};
#pragma unroll
      for (int nf = 0; nf < 4; ++nf)
#pragma unroll
        for (int kf = 0; kf < 2; ++kf)
#pragma unroll
          for (int mf = 0; mf < 2; ++mf)
            s[mf][nf] = __builtin_amdgcn_mfma_f32_16x16x32_bf16(kb[nf][kf], qf[mf][kf], s[mf][nf], 0, 0, 0);

      if (kv0 + 63 > qbase) {
#pragma unroll
        for (int mf = 0; mf < 2; ++mf) {
          const int q = qbase + mf * 16 + l16;
#pragma unroll
          for (int nf = 0; nf < 4; ++nf)
#pragma unroll
            for (int r = 0; r < 4; ++r) {
              const int kv = kv0 + nf * 16 + lhi * 4 + r;
              if (kv > q) s[mf][nf][r] = -1e30f;
            }
        }
      }

#pragma unroll
      for (int mf = 0; mf < 2; ++mf) {
        float lmax = -1e30f;
#pragma unroll
        for (int nf = 0; nf < 4; ++nf)
#pragma unroll
          for (int r = 0; r < 4; ++r) lmax = fmaxf(lmax, s[mf][nf][r]);
        lmax = fmaxf(lmax, __shfl_xor(lmax, 16));
        lmax = fmaxf(lmax, __shfl_xor(lmax, 32));
        const float mnew = fmaxf(m_run[mf], lmax);
        const float corr = exp2f(m_run[mf] - mnew);
        float psum = 0.0f;
#pragma unroll
        for (int nf = 0; nf < 4; ++nf)
#pragma unroll
          for (int r = 0; r < 4; ++r) {
            const float pv = exp2f(s[mf][nf][r] - mnew);
            s[mf][nf][r] = pv;
            psum += pv;
          }
        psum += __shfl_xor(psum, 16);
        psum += __shfl_xor(psum, 32);
        l_run[mf] = l_run[mf] * corr + psum;
        m_run[mf] = mnew;
#pragma unroll
        for (int nf = 0; nf < 4; ++nf) o[mf][nf] *= corr;

        const int q = mf * 16 + l16;
#pragma unroll
        for (int nf = 0; nf < 4; ++nf) {
          const uint32_t u0 = cvt_pk_bf16(s[mf][nf][0], s[mf][nf][1]);
          const uint32_t u1 = cvt_pk_bf16(s[mf][nf][2], s[mf][nf][3]);
          *(uint2*)(pbase + q * 136 + nf * 32 + lhi * 8) = make_uint2(u0, u1);
        }
      }

#pragma unroll
      for (int mf = 0; mf < 2; ++mf) {
        const int q = mf * 16 + l16;
#pragma unroll
        for (int kf = 0; kf < 2; ++kf) {
          const bf16x8 pb = *(const bf16x8*)(pbase + q * 136 + kf * 64 + lhi * 16);
#pragma unroll
          for (int nf = 0; nf < 4; ++nf)
            o[mf][nf] = __builtin_amdgcn_mfma_f32_16x16x32_bf16(vb[nf][kf], pb, o[mf][nf], 0, 0, 0);
        }
      }
    };

    half(qfH, oH, mH, lsH, qbH, pbH);
    if (t < ntL) half(qfL, oL, mL, lsL, qbL, pbL);
  }

  auto epi = [&](f32x4 (&o)[2][4], float (&l_run)[2], const int qbase) {
#pragma unroll
    for (int mf = 0; mf < 2; ++mf) {
      const float inv = 1.0f / l_run[mf];
      const int qrow = qbase + mf * 16 + l16;
      const size_t rb = ((size_t)(b_ * 1024 + qrow)) * 1024 + h_ * 64;
#pragma unroll
      for (int nf = 0; nf < 4; ++nf) {
        const uint32_t u0 = cvt_pk_bf16(o[mf][nf][0] * inv, o[mf][nf][1] * inv);
        const uint32_t u1 = cvt_pk_bf16(o[mf][nf][2] * inv, o[mf][nf][3] * inv);
        *(uint2*)(O + rb + nf * 16 + lhi * 4) = make_uint2(u0, u1);
      }
    }
  };
  epi(oH, lsH, qbH);
  epi(oL, lsL, qbL);
}

extern "C" void kernel_launch(void* const* d_in, const int* in_sizes, int n_in,
                              void* d_out, int out_size, void* d_ws, size_t ws_size,
                              hipStream_t stream) {
  const float* x      = (const float*)d_in[0];
  const float* W_attn = (const float*)d_in[1];
  const float* b_attn = (const float*)d_in[2];
  const float* W_proj = (const float*)d_in[3];
  const float* b_proj = (const float*)d_in[4];
  float* out = (float*)d_out;

  const int M = 8192;       // B*S
  const int E = 1024, N3 = 3072;
  const size_t T = (size_t)M * E;

  char* p = (char*)d_ws;
  ushort_t* xb  = (ushort_t*)p; p += T * 2;              // x bf16; reused as attn_out
  ushort_t* Wab = (ushort_t*)p; p += (size_t)N3 * E * 2; // W_attn^T bf16 [3072][1024]
  ushort_t* Wpb = (ushort_t*)p; p += (size_t)E * E * 2;  // W_proj^T bf16 [1024][1024]
  ushort_t* Qb  = (ushort_t*)p; p += T * 2;              // [BH][S][D]
  ushort_t* Kb  = (ushort_t*)p; p += T * 2;              // [BH][S][D]
  ushort_t* Vtb = (ushort_t*)p; p += T * 2;              // [BH][D][S]

  const float qscale = 0.125f * 1.4426950408889634f;     // 1/sqrt(D) * log2(e)

  cast_x<<<dim3((int)(T / 1024)), dim3(256), 0, stream>>>(x, xb, (int)T);
  transpose_cast<<<dim3(N3 / 32, E / 32), dim3(256), 0, stream>>>(W_attn, Wab, E, N3);
  transpose_cast<<<dim3(E / 32, E / 32), dim3(256), 0, stream>>>(W_proj, Wpb, E, E);
  gemm_bt<2><<<dim3(N3 / 128, M / 128), dim3(256), 0, stream>>>(
      xb, Wab, b_attn, Qb, Kb, Vtb, nullptr, M, N3, E, qscale);
  attn_kernel<<<dim3(512), dim3(256), 0, stream>>>(Qb, Kb, Vtb, xb);
  gemm_bt<1><<<dim3(E / 128, M / 128), dim3(256), 0, stream>>>(
      xb, Wpb, b_proj, nullptr, nullptr, nullptr, out, M, E, E, 1.0f);
}